// Round 14
// baseline (217.781 us; speedup 1.0000x reference)
//
#include <hip/hip_runtime.h>

#define RESO 32
#define R3   32768
#define NB   8
#define PP   131072
#define FF   32
#define HH   128
#define CC   32
#define CAP  64
#define NPTS (NB*PP)    // 1048576 = 2^20
#define NSEG (NB*R3)    // 262144
#define NGRP (NSEG/16)  // 16384 voxel-groups of 16
#define WSLOTS 4096     // 1024 blocks x 4 waves

typedef __attribute__((ext_vector_type(8))) __bf16 bf16x8;
typedef __attribute__((ext_vector_type(4))) float  f32x4;

__device__ __forceinline__ f32x4 MFMA(bf16x8 a, bf16x8 b, f32x4 c) {
    return __builtin_amdgcn_mfma_f32_16x16x32_bf16(a, b, c, 0, 0, 0);
}

// ---- K1: voxel index + bucket fill -------------------------------------
__global__ __launch_bounds__(256) void lpbe_bin(
    const float* __restrict__ points,
    unsigned* __restrict__ count,
    unsigned* __restrict__ bucket,
    float* __restrict__ index_out)
{
    int gid = blockIdx.x * 256 + threadIdx.x;     // 0 .. NPTS-1

    const float* pp = points + (size_t)gid * 3;
    float px = pp[0], py = pp[1], pz = pp[2];
    const float DIV = 1.021f;                     // 1.0 + 0.02 + 0.001 (f32)
    const float HIq = (float)(1.0 - 1e-6);
    float qx = (px - 0.5f)/DIV + 0.5f; qx = fminf(fmaxf(qx, 0.0f), HIq);
    float qy = (py - 0.5f)/DIV + 0.5f; qy = fminf(fmaxf(qy, 0.0f), HIq);
    float qz = (pz - 0.5f)/DIV + 0.5f; qz = fminf(fmaxf(qz, 0.0f), HIq);
    int xi = (int)(qx * 32.0f);
    int yi = (int)(qy * 32.0f);
    int zi = (int)(qz * 32.0f);
    int idx = xi + RESO*(yi + RESO*zi);

    index_out[gid] = (float)idx;

    int seg = (gid >> 17) * R3 + idx;             // PP = 2^17
    unsigned slot = atomicAdd(&count[seg], 1u);
    if (slot < CAP) bucket[(size_t)seg * CAP + slot] = (unsigned)gid;
}

// ---- K2: persistent-block MFMA pool + fused conv ------------------------
// 1024 blocks x 4 waves = 4096 wave-slots; each wave grid-strides over 4
// voxel-groups of 16 (r13 lesson: per-block staging dominates at high block
// counts -> stage once, reuse 4x). r11's best-measured config otherwise:
// 16 vox/wave, 2-deep pipeline, sigma NET trick. w0/conv frags + biases
// persist in registers (~115 VGPR demand < (256,3) cap ~168; r10's spill
// was the (256,4) 64-VGPR cap).
__global__ __launch_bounds__(256, 3) void lpbe_pool(
    const float* __restrict__ feature,
    const float* __restrict__ fc0_w, const float* __restrict__ fc0_b,
    const float* __restrict__ fc1_w, const float* __restrict__ fc1_b,
    const float* __restrict__ sc_w,
    const float* __restrict__ conv_w, const float* __restrict__ conv_b,
    const unsigned* __restrict__ count, const unsigned* __restrict__ bucket,
    float* __restrict__ out)
{
    __shared__ __bf16 s_bsc[8][64*8];     // sc_w  B-frags (natural K)    8 KB
    __shared__ __bf16 s_bw1[8][64*8];     // fc1_w B-frags (sigma K)      8 KB
    __shared__ __bf16 s_pool[4][16*136];  // per-wave pooled tile        17 KB
                                          // total 33 KB

    const int tid  = threadIdx.x;
    const int wv   = tid >> 6;
    const int lane = tid & 63;
    const int c16  = lane & 15;
    const int g    = lane >> 4;           // lane group 0..3

    // ---- stage sc/fc1 fragments into LDS (ONCE per block) ----
    for (int nt = wv; nt < 8; nt += 4) {
        bf16x8 v, w;
        #pragma unroll
        for (int e = 0; e < 8; ++e) {
            int kn = 8*g + e;                                // natural K
            int ks = (e < 4) ? (4*g + e) : (16 + 4*g + e-4); // sigma K
            v[e] = (__bf16)sc_w [kn*HH + 16*nt + c16];
            w[e] = (__bf16)fc1_w[ks*HH + 16*nt + c16];
        }
        *(bf16x8*)&s_bsc[nt][lane*8] = v;
        *(bf16x8*)&s_bw1[nt][lane*8] = w;
    }

    // ---- persistent register fragments ----
    bf16x8 w00, w01;                      // fc0_w column halves
    #pragma unroll
    for (int e = 0; e < 8; ++e) {
        w00[e] = (__bf16)fc0_w[(8*g + e)*FF + c16];
        w01[e] = (__bf16)fc0_w[(8*g + e)*FF + 16 + c16];
    }
    bf16x8 cw0[4], cw1[4];                // conv B-frags
    #pragma unroll
    for (int kk = 0; kk < 4; ++kk) {
        f32x4 a0 = *(const f32x4*)&conv_w[(size_t)c16*HH      + 32*kk + 8*g];
        f32x4 a1 = *(const f32x4*)&conv_w[(size_t)c16*HH      + 32*kk + 8*g + 4];
        f32x4 c0 = *(const f32x4*)&conv_w[(size_t)(16+c16)*HH + 32*kk + 8*g];
        f32x4 c1 = *(const f32x4*)&conv_w[(size_t)(16+c16)*HH + 32*kk + 8*g + 4];
        #pragma unroll
        for (int e = 0; e < 4; ++e) {
            cw0[kk][e] = (__bf16)a0[e]; cw0[kk][4+e] = (__bf16)a1[e];
            cw1[kk][e] = (__bf16)c0[e]; cw1[kk][4+e] = (__bf16)c1[e];
        }
    }

    const f32x4 b0A = *(const f32x4*)&fc0_b[4*g];
    const f32x4 b0B = *(const f32x4*)&fc0_b[16 + 4*g];
    float b1v[8];
    #pragma unroll
    for (int nt = 0; nt < 8; ++nt) b1v[nt] = fc1_b[16*nt + c16];
    const float cb0 = conv_b[c16], cb1 = conv_b[16 + c16];
    __syncthreads();

    const int wslot = blockIdx.x * 4 + wv;      // 0..4095
    __bf16* spool = s_pool[wv];

    // 2-deep rotating pipeline slots (compile-time names -> registers)
    unsigned pid0 = 0, pid1 = 0;
    int kA0 = 0, kB0 = 0, kA1 = 0, kB1 = 0;
    f32x4 fa0, fb0, fa1, fb1;

#define LOADP(PIDX, S) do {                                                  \
    int _Pv = (PIDX);                       /* <= 7 via guards */            \
    kA##S = __builtin_amdgcn_readlane(cntv, 2*_Pv);                          \
    kB##S = __builtin_amdgcn_readlane(cntv, 2*_Pv + 1);                      \
    unsigned _pid = bucket[(size_t)(tb16 + 2*_Pv + (c16 >> 3))*CAP           \
                           + (c16 & 7)];                                     \
    pid##S = _pid & (NPTS - 1);             /* stale/poison-safe */          \
} while (0)

#define LOADF(S) do {                                                        \
    const float* _fp = feature + (size_t)pid##S * FF + 8*g;                  \
    fa##S = *(const f32x4*)_fp;                                              \
    fb##S = *(const f32x4*)(_fp + 4);                                        \
} while (0)

#define STEP(Q, S, SN) do {                                                  \
    const int _q = (Q);                                                      \
    const int _kA = kA##S, _kB = kB##S;                                      \
    if (_q < 6) LOADP(_q + 2, S);       /* pids for pair q+2 */              \
    if (_q < 7) LOADF(SN);              /* features for pair q+1 */          \
    float run[8];                                                            \
    _Pragma("unroll")                                                        \
    for (int nt = 0; nt < 8; ++nt) run[nt] = -3.0e38f;                       \
    int _km = _kA > _kB ? _kA : _kB;                                         \
    int _T  = (_km + 7) >> 3;                                                \
    for (int t = 0; t < _T; ++t) {                                           \
        f32x4 u0, u1;                                                        \
        if (t == 0) { u0 = fa##S; u1 = fb##S; }                              \
        else {                                                               \
            unsigned _pid = bucket[(size_t)(tb16 + 2*_q + (c16 >> 3))*CAP    \
                                   + 8*t + (c16 & 7)] & (NPTS - 1);          \
            const float* _fp = feature + (size_t)_pid * FF + 8*g;            \
            u0 = *(const f32x4*)_fp;                                         \
            u1 = *(const f32x4*)(_fp + 4);                                   \
        }                                                                    \
        bf16x8 ar, aw;                                                       \
        _Pragma("unroll")                                                    \
        for (int e = 0; e < 4; ++e) {                                        \
            ar[e]   = (__bf16)u0[e];            ar[4+e] = (__bf16)u1[e];     \
            aw[e]   = (__bf16)fmaxf(u0[e],0.f); aw[4+e] = (__bf16)fmaxf(u1[e],0.f); \
        }                                                                    \
        f32x4 zz = {0.f,0.f,0.f,0.f};                                        \
        f32x4 n0 = MFMA(w00, aw, zz);   /* NET^T half0: dims 4g+r    */      \
        f32x4 n1 = MFMA(w01, aw, zz);   /* NET^T half1: dims 16+4g+r */      \
        bf16x8 an;                      /* sigma-ordered NET A-frag  */      \
        _Pragma("unroll")                                                    \
        for (int r = 0; r < 4; ++r) {                                        \
            an[r]   = (__bf16)fmaxf(n0[r] + b0A[r], 0.f);                    \
            an[4+r] = (__bf16)fmaxf(n1[r] + b0B[r], 0.f);                    \
        }                                                                    \
        f32x4 mv;                                                            \
        _Pragma("unroll")                                                    \
        for (int r = 0; r < 4; ++r) {                                        \
            int _sl = 8*t + 4*(g & 1) + r;                                   \
            mv[r] = (_sl < ((g < 2) ? _kA : _kB)) ? 0.f : -3.0e38f;          \
        }                                                                    \
        _Pragma("unroll")                                                    \
        for (int nt = 0; nt < 8; ++nt) {                                     \
            bf16x8 bs = *(const bf16x8*)&s_bsc[nt][lane*8];                  \
            bf16x8 bw = *(const bf16x8*)&s_bw1[nt][lane*8];                  \
            f32x4 acc = mv;                                                  \
            acc = MFMA(ar, bs, acc);                                         \
            acc = MFMA(an, bw, acc);                                         \
            run[nt] = fmaxf(run[nt],                                         \
                      fmaxf(fmaxf(acc[0],acc[1]), fmaxf(acc[2],acc[3])));    \
        }                                                                    \
    }                                                                        \
    _Pragma("unroll")                                                        \
    for (int nt = 0; nt < 8; ++nt) {                                         \
        float m = fmaxf(run[nt], __shfl_xor(run[nt], 16));                   \
        float sel = (((g < 2) ? _kA : _kB) == 0) ? 0.f : (m + b1v[nt]);      \
        if (g == 0)      spool[(2*_q  )*136 + 16*nt + c16] = (__bf16)sel;    \
        else if (g == 2) spool[(2*_q+1)*136 + 16*nt + c16] = (__bf16)sel;    \
    }                                                                        \
} while (0)

    // first group's counts
    int tb16 = wslot * 16;
    int cntv = (int)count[tb16 + c16];
    if (cntv > CAP) cntv = CAP;

    #pragma unroll 1
    for (int it = 0; it < NGRP / WSLOTS; ++it) {
        // prefetch next group's counts before this group's work
        int cnt_next = 0;
        if (it + 1 < NGRP / WSLOTS)
            cnt_next = (int)count[tb16 + WSLOTS*16 + c16];

        // pipeline prologue: pids for pairs 0-1, features for pair 0
        LOADP(0, 0);
        LOADF(0);
        LOADP(1, 1);

        STEP(0, 0, 1);
        STEP(1, 1, 0);
        STEP(2, 0, 1);
        STEP(3, 1, 0);
        STEP(4, 0, 1);
        STEP(5, 1, 0);
        STEP(6, 0, 1);
        STEP(7, 1, 0);

        // ---- conv for this group's 16 voxels (wave-local) ----
        asm volatile("s_waitcnt lgkmcnt(0)" ::: "memory");
        f32x4 o0 = {cb0, cb0, cb0, cb0};
        f32x4 o1 = {cb1, cb1, cb1, cb1};
        #pragma unroll
        for (int kk = 0; kk < 4; ++kk) {
            bf16x8 ap = *(const bf16x8*)&spool[c16*136 + 32*kk + 8*g];
            o0 = MFMA(ap, cw0[kk], o0);
            o1 = MFMA(ap, cw1[kk], o1);
        }
        const int n  = tb16 >> 15;              // R3 = 2^15
        const int vb = tb16 & (R3 - 1);
        float* ob = out + (size_t)n*CC*R3 + (size_t)vb + 4*g;
        *(f32x4*)(ob + (size_t)c16*R3)        = o0;
        *(f32x4*)(ob + (size_t)(16 + c16)*R3) = o1;

        tb16 += WSLOTS * 16;
        cntv = cnt_next > CAP ? CAP : cnt_next;
    }

#undef STEP
#undef LOADF
#undef LOADP
}

extern "C" void kernel_launch(void* const* d_in, const int* in_sizes, int n_in,
                              void* d_out, int out_size, void* d_ws, size_t ws_size,
                              hipStream_t stream)
{
    const float* points  = (const float*)d_in[0];
    const float* feature = (const float*)d_in[1];
    const float* fc0_w   = (const float*)d_in[2];
    const float* fc0_b   = (const float*)d_in[3];
    const float* fc1_w   = (const float*)d_in[4];
    const float* fc1_b   = (const float*)d_in[5];
    const float* sc_w    = (const float*)d_in[6];
    const float* conv_w  = (const float*)d_in[7];
    const float* conv_b  = (const float*)d_in[8];

    unsigned* count  = (unsigned*)d_ws;                       // 1 MB
    unsigned* bucket = count + NSEG;                          // 67 MB
    float* out0 = (float*)d_out;                              // index (N,1,P) f32
    float* out1 = out0 + (size_t)NPTS;                        // feature_grid f32

    hipMemsetAsync(count, 0, (size_t)NSEG * sizeof(unsigned), stream);
    lpbe_bin <<<NPTS/256,    256, 0, stream>>>(points, count, bucket, out0);
    lpbe_pool<<<WSLOTS/4,    256, 0, stream>>>(feature, fc0_w, fc0_b, fc1_w, fc1_b,
                                               sc_w, conv_w, conv_b, count, bucket, out1);
}

// Round 15
// 203.237 us; speedup vs baseline: 1.0716x; 1.0716x over previous
//
#include <hip/hip_runtime.h>

#define RESO 32
#define R3   32768
#define NB   8
#define PP   131072
#define FF   32
#define HH   128
#define CC   32
#define CAP  64
#define NPTS (NB*PP)    // 1048576 = 2^20
#define NSEG (NB*R3)    // 262144

typedef __attribute__((ext_vector_type(8))) __bf16 bf16x8;
typedef __attribute__((ext_vector_type(4))) float  f32x4;

__device__ __forceinline__ f32x4 MFMA(bf16x8 a, bf16x8 b, f32x4 c) {
    return __builtin_amdgcn_mfma_f32_16x16x32_bf16(a, b, c, 0, 0, 0);
}

// ---- K1: voxel index + bucket fill -------------------------------------
__global__ __launch_bounds__(256) void lpbe_bin(
    const float* __restrict__ points,
    unsigned* __restrict__ count,
    unsigned* __restrict__ bucket,
    float* __restrict__ index_out)
{
    int gid = blockIdx.x * 256 + threadIdx.x;     // 0 .. NPTS-1

    const float* pp = points + (size_t)gid * 3;
    float px = pp[0], py = pp[1], pz = pp[2];
    const float DIV = 1.021f;                     // 1.0 + 0.02 + 0.001 (f32)
    const float HIq = (float)(1.0 - 1e-6);
    float qx = (px - 0.5f)/DIV + 0.5f; qx = fminf(fmaxf(qx, 0.0f), HIq);
    float qy = (py - 0.5f)/DIV + 0.5f; qy = fminf(fmaxf(qy, 0.0f), HIq);
    float qz = (pz - 0.5f)/DIV + 0.5f; qz = fminf(fmaxf(qz, 0.0f), HIq);
    int xi = (int)(qx * 32.0f);
    int yi = (int)(qy * 32.0f);
    int zi = (int)(qz * 32.0f);
    int idx = xi + RESO*(yi + RESO*zi);

    index_out[gid] = (float)idx;

    int seg = (gid >> 17) * R3 + idx;             // PP = 2^17
    unsigned slot = atomicAdd(&count[seg], 1u);
    if (slot < CAP) bucket[(size_t)seg * CAP + slot] = (unsigned)gid;
}

// ---- K2: MFMA per-voxel recompute + max + fused MFMA conv ---------------
// Exact r11 structure (best measured: pool 124 us) with ONE change: the
// stage-2 nt-loop is split into three explicit passes over a compile-time-
// indexed acc[8] so the 8 (MFMA, dependent-MFMA, dependent-fmax) chains
// become 8-wide independent MFMA clusters (r11's 84-VGPR allocation shows
// the compiler serialized them to save registers: ~18 cyc/MFMA observed).
// The an-repack also moves AFTER pass1 so stage-1 MFMA latency hides there.
__global__ __launch_bounds__(256, 3) void lpbe_pool(
    const float* __restrict__ feature,
    const float* __restrict__ fc0_w, const float* __restrict__ fc0_b,
    const float* __restrict__ fc1_w, const float* __restrict__ fc1_b,
    const float* __restrict__ sc_w,
    const float* __restrict__ conv_w, const float* __restrict__ conv_b,
    const unsigned* __restrict__ count, const unsigned* __restrict__ bucket,
    float* __restrict__ out)
{
    __shared__ __bf16 s_bsc[8][64*8];     // sc_w  B-frags (natural K)    8 KB
    __shared__ __bf16 s_bw1[8][64*8];     // fc1_w B-frags (sigma K)      8 KB
    __shared__ __bf16 s_w0f[2][64*8];     // fc0_w frags (col halves)     2 KB
    __shared__ __bf16 s_pool[4][16*136];  // per-wave pooled tile        17 KB
                                          // total 35.4 KB

    const int tid  = threadIdx.x;
    const int wv   = tid >> 6;
    const int lane = tid & 63;
    const int c16  = lane & 15;
    const int g    = lane >> 4;           // lane group 0..3

    // ---- stage weight fragments into LDS ----
    for (int nt = wv; nt < 8; nt += 4) {
        bf16x8 v, w;
        #pragma unroll
        for (int e = 0; e < 8; ++e) {
            int kn = 8*g + e;                                // natural K
            int ks = (e < 4) ? (4*g + e) : (16 + 4*g + e-4); // sigma K
            v[e] = (__bf16)sc_w [kn*HH + 16*nt + c16];
            w[e] = (__bf16)fc1_w[ks*HH + 16*nt + c16];
        }
        *(bf16x8*)&s_bsc[nt][lane*8] = v;
        *(bf16x8*)&s_bw1[nt][lane*8] = w;
    }
    if (wv < 2) {
        bf16x8 v;
        #pragma unroll
        for (int e = 0; e < 8; ++e)
            v[e] = (__bf16)fc0_w[(8*g + e)*FF + 16*wv + c16];
        *(bf16x8*)&s_w0f[wv][lane*8] = v;
    }

    // per-lane stage-1 biases for dims 4g+r (half0) and 16+4g+r (half1)
    const f32x4 b0A = *(const f32x4*)&fc0_b[4*g];
    const f32x4 b0B = *(const f32x4*)&fc0_b[16 + 4*g];
    float b1v[8];
    #pragma unroll
    for (int nt = 0; nt < 8; ++nt) b1v[nt] = fc1_b[16*nt + c16];
    const float cb0 = conv_b[c16], cb1 = conv_b[16 + c16];
    __syncthreads();

    const int wgid = blockIdx.x * 4 + wv;       // 0..16383
    const int tb16 = wgid * 16;                 // first voxel of this wave
    __bf16* spool = s_pool[wv];

    // all 16 counts of this wave (lane c16 holds its voxel's count)
    int cntv = (int)count[tb16 + c16];
    if (cntv > CAP) cntv = CAP;

    // 2-deep rotating pipeline slots (compile-time names -> registers)
    unsigned pid0 = 0, pid1 = 0;
    int kA0 = 0, kB0 = 0, kA1 = 0, kB1 = 0;
    f32x4 fa0, fb0, fa1, fb1;

#define LOADP(PIDX, S) do {                                                  \
    int _Pv = (PIDX);                       /* <= 7 via guards */            \
    kA##S = __builtin_amdgcn_readlane(cntv, 2*_Pv);                          \
    kB##S = __builtin_amdgcn_readlane(cntv, 2*_Pv + 1);                      \
    unsigned _pid = bucket[(size_t)(tb16 + 2*_Pv + (c16 >> 3))*CAP           \
                           + (c16 & 7)];                                     \
    pid##S = _pid & (NPTS - 1);             /* stale/poison-safe */          \
} while (0)

#define LOADF(S) do {                                                        \
    const float* _fp = feature + (size_t)pid##S * FF + 8*g;                  \
    fa##S = *(const f32x4*)_fp;                                              \
    fb##S = *(const f32x4*)(_fp + 4);                                        \
} while (0)

#define STEP(Q, S, SN) do {                                                  \
    const int _q = (Q);                                                      \
    const int _kA = kA##S, _kB = kB##S;                                      \
    if (_q < 6) LOADP(_q + 2, S);       /* pids for pair q+2 */              \
    if (_q < 7) LOADF(SN);              /* features for pair q+1 */          \
    float run[8];                                                            \
    _Pragma("unroll")                                                        \
    for (int nt = 0; nt < 8; ++nt) run[nt] = -3.0e38f;                       \
    int _km = _kA > _kB ? _kA : _kB;                                         \
    int _T  = (_km + 7) >> 3;                                                \
    for (int t = 0; t < _T; ++t) {                                           \
        f32x4 u0, u1;                                                        \
        if (t == 0) { u0 = fa##S; u1 = fb##S; }                              \
        else {                                                               \
            unsigned _pid = bucket[(size_t)(tb16 + 2*_q + (c16 >> 3))*CAP    \
                                   + 8*t + (c16 & 7)] & (NPTS - 1);          \
            const float* _fp = feature + (size_t)_pid * FF + 8*g;            \
            u0 = *(const f32x4*)_fp;                                         \
            u1 = *(const f32x4*)(_fp + 4);                                   \
        }                                                                    \
        bf16x8 ar, aw;                                                       \
        _Pragma("unroll")                                                    \
        for (int e = 0; e < 4; ++e) {                                        \
            ar[e]   = (__bf16)u0[e];            ar[4+e] = (__bf16)u1[e];     \
            aw[e]   = (__bf16)fmaxf(u0[e],0.f); aw[4+e] = (__bf16)fmaxf(u1[e],0.f); \
        }                                                                    \
        bf16x8 w00 = *(const bf16x8*)&s_w0f[0][lane*8];                      \
        bf16x8 w01 = *(const bf16x8*)&s_w0f[1][lane*8];                      \
        f32x4 zz = {0.f,0.f,0.f,0.f};                                        \
        f32x4 n0 = MFMA(w00, aw, zz);   /* NET^T half0: dims 4g+r    */      \
        f32x4 n1 = MFMA(w01, aw, zz);   /* NET^T half1: dims 16+4g+r */      \
        f32x4 mv;                                                            \
        _Pragma("unroll")                                                    \
        for (int r = 0; r < 4; ++r) {                                        \
            int _sl = 8*t + 4*(g & 1) + r;                                   \
            mv[r] = (_sl < ((g < 2) ? _kA : _kB)) ? 0.f : -3.0e38f;          \
        }                                                                    \
        /* pass 1: 8 independent MFMAs (no dep on n0/n1) */                  \
        f32x4 acc[8];                                                        \
        _Pragma("unroll")                                                    \
        for (int nt = 0; nt < 8; ++nt) {                                     \
            bf16x8 bs = *(const bf16x8*)&s_bsc[nt][lane*8];                  \
            acc[nt] = MFMA(ar, bs, mv);                                      \
        }                                                                    \
        /* an repack: n0/n1 latency hidden under pass 1 */                   \
        bf16x8 an;                      /* sigma-ordered NET A-frag  */      \
        _Pragma("unroll")                                                    \
        for (int r = 0; r < 4; ++r) {                                        \
            an[r]   = (__bf16)fmaxf(n0[r] + b0A[r], 0.f);                    \
            an[4+r] = (__bf16)fmaxf(n1[r] + b0B[r], 0.f);                    \
        }                                                                    \
        /* pass 2: 8 independent MFMAs (deps on pass-1 results, spaced) */   \
        _Pragma("unroll")                                                    \
        for (int nt = 0; nt < 8; ++nt) {                                     \
            bf16x8 bw = *(const bf16x8*)&s_bw1[nt][lane*8];                  \
            acc[nt] = MFMA(an, bw, acc[nt]);                                 \
        }                                                                    \
        /* pass 3: reductions */                                             \
        _Pragma("unroll")                                                    \
        for (int nt = 0; nt < 8; ++nt) {                                     \
            run[nt] = fmaxf(run[nt],                                         \
                      fmaxf(fmaxf(acc[nt][0],acc[nt][1]),                    \
                            fmaxf(acc[nt][2],acc[nt][3])));                  \
        }                                                                    \
    }                                                                        \
    _Pragma("unroll")                                                        \
    for (int nt = 0; nt < 8; ++nt) {                                         \
        float m = fmaxf(run[nt], __shfl_xor(run[nt], 16));                   \
        float sel = (((g < 2) ? _kA : _kB) == 0) ? 0.f : (m + b1v[nt]);      \
        if (g == 0)      spool[(2*_q  )*136 + 16*nt + c16] = (__bf16)sel;    \
        else if (g == 2) spool[(2*_q+1)*136 + 16*nt + c16] = (__bf16)sel;    \
    }                                                                        \
} while (0)

    // pipeline prologue: pids for pairs 0-1, features for pair 0
    LOADP(0, 0);
    LOADF(0);
    LOADP(1, 1);

    STEP(0, 0, 1);
    STEP(1, 1, 0);
    STEP(2, 0, 1);
    STEP(3, 1, 0);
    STEP(4, 0, 1);
    STEP(5, 1, 0);
    STEP(6, 0, 1);
    STEP(7, 1, 0);

    // ---- conv for this wave's 16 voxels via MFMA ----
    // B-frags rebuilt from L2-hot conv_w (16 KB, read by all blocks)
    bf16x8 cw0[4], cw1[4];
    #pragma unroll
    for (int kk = 0; kk < 4; ++kk) {
        f32x4 a0 = *(const f32x4*)&conv_w[(size_t)c16*HH      + 32*kk + 8*g];
        f32x4 a1 = *(const f32x4*)&conv_w[(size_t)c16*HH      + 32*kk + 8*g + 4];
        f32x4 c0 = *(const f32x4*)&conv_w[(size_t)(16+c16)*HH + 32*kk + 8*g];
        f32x4 c1 = *(const f32x4*)&conv_w[(size_t)(16+c16)*HH + 32*kk + 8*g + 4];
        #pragma unroll
        for (int e = 0; e < 4; ++e) {
            cw0[kk][e] = (__bf16)a0[e]; cw0[kk][4+e] = (__bf16)a1[e];
            cw1[kk][e] = (__bf16)c0[e]; cw1[kk][4+e] = (__bf16)c1[e];
        }
    }
    asm volatile("s_waitcnt lgkmcnt(0)" ::: "memory");
    f32x4 o0 = {cb0, cb0, cb0, cb0};
    f32x4 o1 = {cb1, cb1, cb1, cb1};
    #pragma unroll
    for (int kk = 0; kk < 4; ++kk) {
        bf16x8 ap = *(const bf16x8*)&spool[c16*136 + 32*kk + 8*g];
        o0 = MFMA(ap, cw0[kk], o0);
        o1 = MFMA(ap, cw1[kk], o1);
    }
    const int n  = tb16 >> 15;              // R3 = 2^15
    const int vb = tb16 & (R3 - 1);
    float* ob = out + (size_t)n*CC*R3 + (size_t)vb + 4*g;
    *(f32x4*)(ob + (size_t)c16*R3)        = o0;
    *(f32x4*)(ob + (size_t)(16 + c16)*R3) = o1;

#undef STEP
#undef LOADF
#undef LOADP
}

extern "C" void kernel_launch(void* const* d_in, const int* in_sizes, int n_in,
                              void* d_out, int out_size, void* d_ws, size_t ws_size,
                              hipStream_t stream)
{
    const float* points  = (const float*)d_in[0];
    const float* feature = (const float*)d_in[1];
    const float* fc0_w   = (const float*)d_in[2];
    const float* fc0_b   = (const float*)d_in[3];
    const float* fc1_w   = (const float*)d_in[4];
    const float* fc1_b   = (const float*)d_in[5];
    const float* sc_w    = (const float*)d_in[6];
    const float* conv_w  = (const float*)d_in[7];
    const float* conv_b  = (const float*)d_in[8];

    unsigned* count  = (unsigned*)d_ws;                       // 1 MB
    unsigned* bucket = count + NSEG;                          // 67 MB
    float* out0 = (float*)d_out;                              // index (N,1,P) f32
    float* out1 = out0 + (size_t)NPTS;                        // feature_grid f32

    hipMemsetAsync(count, 0, (size_t)NSEG * sizeof(unsigned), stream);
    lpbe_bin <<<NPTS/256, 256, 0, stream>>>(points, count, bucket, out0);
    lpbe_pool<<<NSEG/64,  256, 0, stream>>>(feature, fc0_w, fc0_b, fc1_w, fc1_b,
                                            sc_w, conv_w, conv_b, count, bucket, out1);
}

// Round 17
// 181.310 us; speedup vs baseline: 1.2011x; 1.1209x over previous
//
#include <hip/hip_runtime.h>

#define RESO 32
#define R3   32768
#define NB   8
#define PP   131072
#define FF   32
#define HH   128
#define CC   32
#define CAP  64
#define NPTS (NB*PP)    // 1048576 = 2^20
#define NSEG (NB*R3)    // 262144

// wbuf: pre-swizzled bf16 weight fragments (built by lpbe_prep each launch)
#define OFF_BSC 0        // 8 frag-sets x 512
#define OFF_BW1 4096     // 8 frag-sets x 512 (sigma-K)
#define OFF_W0F 8192     // 2 halves    x 512
#define OFF_CWF 9216     // 8 frag-sets x 512
#define WBUF_N  13312    // bf16 elements (26 KB)

typedef __attribute__((ext_vector_type(8))) __bf16 bf16x8;
typedef __attribute__((ext_vector_type(4))) float  f32x4;

__device__ __forceinline__ f32x4 MFMA(bf16x8 a, bf16x8 b, f32x4 c) {
    return __builtin_amdgcn_mfma_f32_16x16x32_bf16(a, b, c, 0, 0, 0);
}

// ---- K0: build fragment-layout weight buffer (1 block, trivial cost) ----
__global__ __launch_bounds__(256) void lpbe_prep(
    const float* __restrict__ fc0_w, const float* __restrict__ fc1_w,
    const float* __restrict__ sc_w,  const float* __restrict__ conv_w,
    __bf16* __restrict__ wbuf)
{
    for (int idx = threadIdx.x; idx < WBUF_N; idx += 256) {
        float v;
        if (idx < OFF_BW1) {                      // bsc (natural K)
            int nt = idx >> 9, r = idx & 511, lane = r >> 3, e = r & 7;
            int c16 = lane & 15, g = lane >> 4;
            v = sc_w[(8*g + e)*HH + 16*nt + c16];
        } else if (idx < OFF_W0F) {               // bw1 (sigma K)
            int j = idx - OFF_BW1;
            int nt = j >> 9, r = j & 511, lane = r >> 3, e = r & 7;
            int c16 = lane & 15, g = lane >> 4;
            int ks = (e < 4) ? (4*g + e) : (16 + 4*g + e - 4);
            v = fc1_w[ks*HH + 16*nt + c16];
        } else if (idx < OFF_CWF) {               // w0 column halves
            int j = idx - OFF_W0F;
            int h = j >> 9, r = j & 511, lane = r >> 3, e = r & 7;
            int c16 = lane & 15, g = lane >> 4;
            v = fc0_w[(8*g + e)*FF + 16*h + c16];
        } else {                                  // conv frags
            int j = idx - OFF_CWF;
            int fi = j >> 9, r = j & 511, lane = r >> 3, e = r & 7;
            int c16 = lane & 15, g = lane >> 4;
            v = conv_w[(16*(fi >> 2) + c16)*HH + 32*(fi & 3) + 8*g + e];
        }
        wbuf[idx] = (__bf16)v;
    }
}

// ---- K1: voxel index + bucket fill -------------------------------------
__global__ __launch_bounds__(256) void lpbe_bin(
    const float* __restrict__ points,
    unsigned* __restrict__ count,
    unsigned* __restrict__ bucket,
    float* __restrict__ index_out)
{
    int gid = blockIdx.x * 256 + threadIdx.x;     // 0 .. NPTS-1

    const float* pp = points + (size_t)gid * 3;
    float px = pp[0], py = pp[1], pz = pp[2];
    const float DIV = 1.021f;                     // 1.0 + 0.02 + 0.001 (f32)
    const float HIq = (float)(1.0 - 1e-6);
    float qx = (px - 0.5f)/DIV + 0.5f; qx = fminf(fmaxf(qx, 0.0f), HIq);
    float qy = (py - 0.5f)/DIV + 0.5f; qy = fminf(fmaxf(qy, 0.0f), HIq);
    float qz = (pz - 0.5f)/DIV + 0.5f; qz = fminf(fmaxf(qz, 0.0f), HIq);
    int xi = (int)(qx * 32.0f);
    int yi = (int)(qy * 32.0f);
    int zi = (int)(qz * 32.0f);
    int idx = xi + RESO*(yi + RESO*zi);

    index_out[gid] = (float)idx;

    int seg = (gid >> 17) * R3 + idx;             // PP = 2^17
    unsigned slot = atomicAdd(&count[seg], 1u);
    if (slot < CAP) bucket[(size_t)seg * CAP + slot] = (unsigned)gid;
}

// ---- K2: MFMA per-voxel recompute + max + fused MFMA conv ---------------
// EXACT r11 structure (champion: pool 124 us) with one change: weight
// fragments are pre-swizzled to bf16 in wbuf by lpbe_prep, so per-block
// staging is a coalesced 16B-per-lane memcpy (7 uint4 copies/thread)
// instead of ~144 scattered scalar loads + cvts, and the conv tail reads
// LDS fragments instead of rebuilding from global. No added register
// lifetime anywhere (r10/r14/r15 lesson: added live state => spills).
__global__ __launch_bounds__(256, 3) void lpbe_pool(
    const float* __restrict__ feature,
    const float* __restrict__ fc0_b, const float* __restrict__ fc1_b,
    const float* __restrict__ conv_b,
    const __bf16* __restrict__ wbuf,
    const unsigned* __restrict__ count, const unsigned* __restrict__ bucket,
    float* __restrict__ out)
{
    __shared__ __bf16 s_w[WBUF_N];        // all weight fragments      26 KB
    __shared__ __bf16 s_pool[4][16*136];  // per-wave pooled tile      17 KB
                                          // total 43.4 KB -> 3 blocks/CU

    const int tid  = threadIdx.x;
    const int wv   = tid >> 6;
    const int lane = tid & 63;
    const int c16  = lane & 15;
    const int g    = lane >> 4;           // lane group 0..3

    // ---- stage all fragments: coalesced vector copy ----
    {
        const uint4* src = (const uint4*)wbuf;
        uint4* dst = (uint4*)s_w;
        #pragma unroll
        for (int i = 0; i < 7; ++i) {
            int j = tid + 256*i;
            if (j < WBUF_N/8) dst[j] = src[j];
        }
    }

    // per-lane stage-1 biases for dims 4g+r (half0) and 16+4g+r (half1)
    const f32x4 b0A = *(const f32x4*)&fc0_b[4*g];
    const f32x4 b0B = *(const f32x4*)&fc0_b[16 + 4*g];
    float b1v[8];
    #pragma unroll
    for (int nt = 0; nt < 8; ++nt) b1v[nt] = fc1_b[16*nt + c16];
    const float cb0 = conv_b[c16], cb1 = conv_b[16 + c16];
    __syncthreads();

    const int wgid = blockIdx.x * 4 + wv;       // 0..16383
    const int tb16 = wgid * 16;                 // first voxel of this wave
    __bf16* spool = s_pool[wv];

    // all 16 counts of this wave (lane c16 holds its voxel's count)
    int cntv = (int)count[tb16 + c16];
    if (cntv > CAP) cntv = CAP;

    // 2-deep rotating pipeline slots (compile-time names -> registers)
    unsigned pid0 = 0, pid1 = 0;
    int kA0 = 0, kB0 = 0, kA1 = 0, kB1 = 0;
    f32x4 fa0, fb0, fa1, fb1;

#define LOADP(PIDX, S) do {                                                  \
    int _Pv = (PIDX);                       /* <= 7 via guards */            \
    kA##S = __builtin_amdgcn_readlane(cntv, 2*_Pv);                          \
    kB##S = __builtin_amdgcn_readlane(cntv, 2*_Pv + 1);                      \
    unsigned _pid = bucket[(size_t)(tb16 + 2*_Pv + (c16 >> 3))*CAP           \
                           + (c16 & 7)];                                     \
    pid##S = _pid & (NPTS - 1);             /* stale/poison-safe */          \
} while (0)

#define LOADF(S) do {                                                        \
    const float* _fp = feature + (size_t)pid##S * FF + 8*g;                  \
    fa##S = *(const f32x4*)_fp;                                              \
    fb##S = *(const f32x4*)(_fp + 4);                                        \
} while (0)

#define STEP(Q, S, SN) do {                                                  \
    const int _q = (Q);                                                      \
    const int _kA = kA##S, _kB = kB##S;                                      \
    if (_q < 6) LOADP(_q + 2, S);       /* pids for pair q+2 */              \
    if (_q < 7) LOADF(SN);              /* features for pair q+1 */          \
    float run[8];                                                            \
    _Pragma("unroll")                                                        \
    for (int nt = 0; nt < 8; ++nt) run[nt] = -3.0e38f;                       \
    int _km = _kA > _kB ? _kA : _kB;                                         \
    int _T  = (_km + 7) >> 3;                                                \
    for (int t = 0; t < _T; ++t) {                                           \
        f32x4 u0, u1;                                                        \
        if (t == 0) { u0 = fa##S; u1 = fb##S; }                              \
        else {                                                               \
            unsigned _pid = bucket[(size_t)(tb16 + 2*_q + (c16 >> 3))*CAP    \
                                   + 8*t + (c16 & 7)] & (NPTS - 1);          \
            const float* _fp = feature + (size_t)_pid * FF + 8*g;            \
            u0 = *(const f32x4*)_fp;                                         \
            u1 = *(const f32x4*)(_fp + 4);                                   \
        }                                                                    \
        bf16x8 ar, aw;                                                       \
        _Pragma("unroll")                                                    \
        for (int e = 0; e < 4; ++e) {                                        \
            ar[e]   = (__bf16)u0[e];            ar[4+e] = (__bf16)u1[e];     \
            aw[e]   = (__bf16)fmaxf(u0[e],0.f); aw[4+e] = (__bf16)fmaxf(u1[e],0.f); \
        }                                                                    \
        bf16x8 w00 = *(const bf16x8*)&s_w[OFF_W0F       + lane*8];           \
        bf16x8 w01 = *(const bf16x8*)&s_w[OFF_W0F + 512 + lane*8];           \
        f32x4 zz = {0.f,0.f,0.f,0.f};                                        \
        f32x4 n0 = MFMA(w00, aw, zz);   /* NET^T half0: dims 4g+r    */      \
        f32x4 n1 = MFMA(w01, aw, zz);   /* NET^T half1: dims 16+4g+r */      \
        bf16x8 an;                      /* sigma-ordered NET A-frag  */      \
        _Pragma("unroll")                                                    \
        for (int r = 0; r < 4; ++r) {                                        \
            an[r]   = (__bf16)fmaxf(n0[r] + b0A[r], 0.f);                    \
            an[4+r] = (__bf16)fmaxf(n1[r] + b0B[r], 0.f);                    \
        }                                                                    \
        f32x4 mv;                                                            \
        _Pragma("unroll")                                                    \
        for (int r = 0; r < 4; ++r) {                                        \
            int _sl = 8*t + 4*(g & 1) + r;                                   \
            mv[r] = (_sl < ((g < 2) ? _kA : _kB)) ? 0.f : -3.0e38f;          \
        }                                                                    \
        _Pragma("unroll")                                                    \
        for (int nt = 0; nt < 8; ++nt) {                                     \
            bf16x8 bs = *(const bf16x8*)&s_w[OFF_BSC + nt*512 + lane*8];     \
            bf16x8 bw = *(const bf16x8*)&s_w[OFF_BW1 + nt*512 + lane*8];     \
            f32x4 acc = mv;                                                  \
            acc = MFMA(ar, bs, acc);                                         \
            acc = MFMA(an, bw, acc);                                         \
            run[nt] = fmaxf(run[nt],                                         \
                      fmaxf(fmaxf(acc[0],acc[1]), fmaxf(acc[2],acc[3])));    \
        }                                                                    \
    }                                                                        \
    _Pragma("unroll")                                                        \
    for (int nt = 0; nt < 8; ++nt) {                                         \
        float m = fmaxf(run[nt], __shfl_xor(run[nt], 16));                   \
        float sel = (((g < 2) ? _kA : _kB) == 0) ? 0.f : (m + b1v[nt]);      \
        if (g == 0)      spool[(2*_q  )*136 + 16*nt + c16] = (__bf16)sel;    \
        else if (g == 2) spool[(2*_q+1)*136 + 16*nt + c16] = (__bf16)sel;    \
    }                                                                        \
} while (0)

    // pipeline prologue: pids for pairs 0-1, features for pair 0
    LOADP(0, 0);
    LOADF(0);
    LOADP(1, 1);

    STEP(0, 0, 1);
    STEP(1, 1, 0);
    STEP(2, 0, 1);
    STEP(3, 1, 0);
    STEP(4, 0, 1);
    STEP(5, 1, 0);
    STEP(6, 0, 1);
    STEP(7, 1, 0);

    // ---- conv for this wave's 16 voxels via MFMA (frags from LDS) ----
    asm volatile("s_waitcnt lgkmcnt(0)" ::: "memory");
    f32x4 o0 = {cb0, cb0, cb0, cb0};
    f32x4 o1 = {cb1, cb1, cb1, cb1};
    #pragma unroll
    for (int kk = 0; kk < 4; ++kk) {
        bf16x8 ap  = *(const bf16x8*)&spool[c16*136 + 32*kk + 8*g];
        bf16x8 bc0 = *(const bf16x8*)&s_w[OFF_CWF + kk*512       + lane*8];
        bf16x8 bc1 = *(const bf16x8*)&s_w[OFF_CWF + (4+kk)*512   + lane*8];
        o0 = MFMA(ap, bc0, o0);
        o1 = MFMA(ap, bc1, o1);
    }
    const int n  = tb16 >> 15;              // R3 = 2^15
    const int vb = tb16 & (R3 - 1);
    float* ob = out + (size_t)n*CC*R3 + (size_t)vb + 4*g;
    *(f32x4*)(ob + (size_t)c16*R3)        = o0;
    *(f32x4*)(ob + (size_t)(16 + c16)*R3) = o1;

#undef STEP
#undef LOADF
#undef LOADP
}

extern "C" void kernel_launch(void* const* d_in, const int* in_sizes, int n_in,
                              void* d_out, int out_size, void* d_ws, size_t ws_size,
                              hipStream_t stream)
{
    const float* points  = (const float*)d_in[0];
    const float* feature = (const float*)d_in[1];
    const float* fc0_w   = (const float*)d_in[2];
    const float* fc0_b   = (const float*)d_in[3];
    const float* fc1_w   = (const float*)d_in[4];
    const float* fc1_b   = (const float*)d_in[5];
    const float* sc_w    = (const float*)d_in[6];
    const float* conv_w  = (const float*)d_in[7];
    const float* conv_b  = (const float*)d_in[8];

    unsigned* count  = (unsigned*)d_ws;                       // 1 MB
    unsigned* bucket = count + NSEG;                          // 67 MB
    __bf16* wbuf = (__bf16*)(bucket + (size_t)NSEG * CAP);    // 26 KB
    float* out0 = (float*)d_out;                              // index (N,1,P) f32
    float* out1 = out0 + (size_t)NPTS;                        // feature_grid f32

    lpbe_prep<<<1, 256, 0, stream>>>(fc0_w, fc1_w, sc_w, conv_w, wbuf);
    hipMemsetAsync(count, 0, (size_t)NSEG * sizeof(unsigned), stream);
    lpbe_bin <<<NPTS/256, 256, 0, stream>>>(points, count, bucket, out0);
    lpbe_pool<<<NSEG/64,  256, 0, stream>>>(feature, fc0_b, fc1_b, conv_b,
                                            wbuf, count, bucket, out1);
}

// Round 18
// 171.796 us; speedup vs baseline: 1.2677x; 1.0554x over previous
//
#include <hip/hip_runtime.h>

#define RESO 32
#define R3   32768
#define NB   8
#define PP   131072
#define FF   32
#define HH   128
#define CC   32
#define CAP  64
#define NPTS (NB*PP)    // 1048576 = 2^20
#define NSEG (NB*R3)    // 262144

// wbuf: pre-swizzled bf16 weight fragments (built inside lpbe_bin's extra block)
#define OFF_BSC 0        // 8 frag-sets x 512
#define OFF_BW1 4096     // 8 frag-sets x 512 (sigma-K)
#define OFF_W0F 8192     // 2 halves    x 512
#define OFF_CWF 9216     // 8 frag-sets x 512
#define WBUF_N  13312    // bf16 elements (26 KB)

typedef __attribute__((ext_vector_type(8))) __bf16 bf16x8;
typedef __attribute__((ext_vector_type(4))) float  f32x4;

__device__ __forceinline__ f32x4 MFMA(bf16x8 a, bf16x8 b, f32x4 c) {
    return __builtin_amdgcn_mfma_f32_16x16x32_bf16(a, b, c, 0, 0, 0);
}

// ---- K1: voxel index + bucket fill; LAST block builds wbuf instead ------
__global__ __launch_bounds__(256) void lpbe_bin(
    const float* __restrict__ points,
    unsigned* __restrict__ count,
    unsigned* __restrict__ bucket,
    float* __restrict__ index_out,
    const float* __restrict__ fc0_w, const float* __restrict__ fc1_w,
    const float* __restrict__ sc_w,  const float* __restrict__ conv_w,
    __bf16* __restrict__ wbuf)
{
    if (blockIdx.x == NPTS/256) {
        // ---- weight-fragment prep (one block; ~52 elems/thread) ----
        for (int idx = threadIdx.x; idx < WBUF_N; idx += 256) {
            float v;
            if (idx < OFF_BW1) {                      // bsc (natural K)
                int nt = idx >> 9, r = idx & 511, lane = r >> 3, e = r & 7;
                int c16 = lane & 15, g = lane >> 4;
                v = sc_w[(8*g + e)*HH + 16*nt + c16];
            } else if (idx < OFF_W0F) {               // bw1 (sigma K)
                int j = idx - OFF_BW1;
                int nt = j >> 9, r = j & 511, lane = r >> 3, e = r & 7;
                int c16 = lane & 15, g = lane >> 4;
                int ks = (e < 4) ? (4*g + e) : (16 + 4*g + e - 4);
                v = fc1_w[ks*HH + 16*nt + c16];
            } else if (idx < OFF_CWF) {               // w0 column halves
                int j = idx - OFF_W0F;
                int h = j >> 9, r = j & 511, lane = r >> 3, e = r & 7;
                int c16 = lane & 15, g = lane >> 4;
                v = fc0_w[(8*g + e)*FF + 16*h + c16];
            } else {                                  // conv frags
                int j = idx - OFF_CWF;
                int fi = j >> 9, r = j & 511, lane = r >> 3, e = r & 7;
                int c16 = lane & 15, g = lane >> 4;
                v = conv_w[(16*(fi >> 2) + c16)*HH + 32*(fi & 3) + 8*g + e];
            }
            wbuf[idx] = (__bf16)v;
        }
        return;
    }

    int gid = blockIdx.x * 256 + threadIdx.x;     // 0 .. NPTS-1

    const float* pp = points + (size_t)gid * 3;
    float px = pp[0], py = pp[1], pz = pp[2];
    const float DIV = 1.021f;                     // 1.0 + 0.02 + 0.001 (f32)
    const float HIq = (float)(1.0 - 1e-6);
    float qx = (px - 0.5f)/DIV + 0.5f; qx = fminf(fmaxf(qx, 0.0f), HIq);
    float qy = (py - 0.5f)/DIV + 0.5f; qy = fminf(fmaxf(qy, 0.0f), HIq);
    float qz = (pz - 0.5f)/DIV + 0.5f; qz = fminf(fmaxf(qz, 0.0f), HIq);
    int xi = (int)(qx * 32.0f);
    int yi = (int)(qy * 32.0f);
    int zi = (int)(qz * 32.0f);
    int idx = xi + RESO*(yi + RESO*zi);

    index_out[gid] = (float)idx;

    int seg = (gid >> 17) * R3 + idx;             // PP = 2^17
    unsigned slot = atomicAdd(&count[seg], 1u);
    if (slot < CAP) bucket[(size_t)seg * CAP + slot] = (unsigned)gid;
}

// ---- K2: MFMA per-voxel recompute + max + fused MFMA conv ---------------
// r17 pool (best measured: 121.6 us), byte-identical. Weight fragments are
// pre-swizzled bf16 in wbuf -> per-block staging is a coalesced vector
// memcpy; conv tail reads LDS fragments. No added register lifetime
// (r10/r14/r15 lesson: any added live state => scratch spills at the
// compiler's 84-VGPR operating point).
__global__ __launch_bounds__(256, 3) void lpbe_pool(
    const float* __restrict__ feature,
    const float* __restrict__ fc0_b, const float* __restrict__ fc1_b,
    const float* __restrict__ conv_b,
    const __bf16* __restrict__ wbuf,
    const unsigned* __restrict__ count, const unsigned* __restrict__ bucket,
    float* __restrict__ out)
{
    __shared__ __bf16 s_w[WBUF_N];        // all weight fragments      26 KB
    __shared__ __bf16 s_pool[4][16*136];  // per-wave pooled tile      17 KB
                                          // total 43.4 KB -> 3 blocks/CU

    const int tid  = threadIdx.x;
    const int wv   = tid >> 6;
    const int lane = tid & 63;
    const int c16  = lane & 15;
    const int g    = lane >> 4;           // lane group 0..3

    // ---- stage all fragments: coalesced vector copy ----
    {
        const uint4* src = (const uint4*)wbuf;
        uint4* dst = (uint4*)s_w;
        #pragma unroll
        for (int i = 0; i < 7; ++i) {
            int j = tid + 256*i;
            if (j < WBUF_N/8) dst[j] = src[j];
        }
    }

    // per-lane stage-1 biases for dims 4g+r (half0) and 16+4g+r (half1)
    const f32x4 b0A = *(const f32x4*)&fc0_b[4*g];
    const f32x4 b0B = *(const f32x4*)&fc0_b[16 + 4*g];
    float b1v[8];
    #pragma unroll
    for (int nt = 0; nt < 8; ++nt) b1v[nt] = fc1_b[16*nt + c16];
    const float cb0 = conv_b[c16], cb1 = conv_b[16 + c16];
    __syncthreads();

    const int wgid = blockIdx.x * 4 + wv;       // 0..16383
    const int tb16 = wgid * 16;                 // first voxel of this wave
    __bf16* spool = s_pool[wv];

    // all 16 counts of this wave (lane c16 holds its voxel's count)
    int cntv = (int)count[tb16 + c16];
    if (cntv > CAP) cntv = CAP;

    // 2-deep rotating pipeline slots (compile-time names -> registers)
    unsigned pid0 = 0, pid1 = 0;
    int kA0 = 0, kB0 = 0, kA1 = 0, kB1 = 0;
    f32x4 fa0, fb0, fa1, fb1;

#define LOADP(PIDX, S) do {                                                  \
    int _Pv = (PIDX);                       /* <= 7 via guards */            \
    kA##S = __builtin_amdgcn_readlane(cntv, 2*_Pv);                          \
    kB##S = __builtin_amdgcn_readlane(cntv, 2*_Pv + 1);                      \
    unsigned _pid = bucket[(size_t)(tb16 + 2*_Pv + (c16 >> 3))*CAP           \
                           + (c16 & 7)];                                     \
    pid##S = _pid & (NPTS - 1);             /* stale/poison-safe */          \
} while (0)

#define LOADF(S) do {                                                        \
    const float* _fp = feature + (size_t)pid##S * FF + 8*g;                  \
    fa##S = *(const f32x4*)_fp;                                              \
    fb##S = *(const f32x4*)(_fp + 4);                                        \
} while (0)

#define STEP(Q, S, SN) do {                                                  \
    const int _q = (Q);                                                      \
    const int _kA = kA##S, _kB = kB##S;                                      \
    if (_q < 6) LOADP(_q + 2, S);       /* pids for pair q+2 */              \
    if (_q < 7) LOADF(SN);              /* features for pair q+1 */          \
    float run[8];                                                            \
    _Pragma("unroll")                                                        \
    for (int nt = 0; nt < 8; ++nt) run[nt] = -3.0e38f;                       \
    int _km = _kA > _kB ? _kA : _kB;                                         \
    int _T  = (_km + 7) >> 3;                                                \
    for (int t = 0; t < _T; ++t) {                                           \
        f32x4 u0, u1;                                                        \
        if (t == 0) { u0 = fa##S; u1 = fb##S; }                              \
        else {                                                               \
            unsigned _pid = bucket[(size_t)(tb16 + 2*_q + (c16 >> 3))*CAP    \
                                   + 8*t + (c16 & 7)] & (NPTS - 1);          \
            const float* _fp = feature + (size_t)_pid * FF + 8*g;            \
            u0 = *(const f32x4*)_fp;                                         \
            u1 = *(const f32x4*)(_fp + 4);                                   \
        }                                                                    \
        bf16x8 ar, aw;                                                       \
        _Pragma("unroll")                                                    \
        for (int e = 0; e < 4; ++e) {                                        \
            ar[e]   = (__bf16)u0[e];            ar[4+e] = (__bf16)u1[e];     \
            aw[e]   = (__bf16)fmaxf(u0[e],0.f); aw[4+e] = (__bf16)fmaxf(u1[e],0.f); \
        }                                                                    \
        bf16x8 w00 = *(const bf16x8*)&s_w[OFF_W0F       + lane*8];           \
        bf16x8 w01 = *(const bf16x8*)&s_w[OFF_W0F + 512 + lane*8];           \
        f32x4 zz = {0.f,0.f,0.f,0.f};                                        \
        f32x4 n0 = MFMA(w00, aw, zz);   /* NET^T half0: dims 4g+r    */      \
        f32x4 n1 = MFMA(w01, aw, zz);   /* NET^T half1: dims 16+4g+r */      \
        bf16x8 an;                      /* sigma-ordered NET A-frag  */      \
        _Pragma("unroll")                                                    \
        for (int r = 0; r < 4; ++r) {                                        \
            an[r]   = (__bf16)fmaxf(n0[r] + b0A[r], 0.f);                    \
            an[4+r] = (__bf16)fmaxf(n1[r] + b0B[r], 0.f);                    \
        }                                                                    \
        f32x4 mv;                                                            \
        _Pragma("unroll")                                                    \
        for (int r = 0; r < 4; ++r) {                                        \
            int _sl = 8*t + 4*(g & 1) + r;                                   \
            mv[r] = (_sl < ((g < 2) ? _kA : _kB)) ? 0.f : -3.0e38f;          \
        }                                                                    \
        _Pragma("unroll")                                                    \
        for (int nt = 0; nt < 8; ++nt) {                                     \
            bf16x8 bs = *(const bf16x8*)&s_w[OFF_BSC + nt*512 + lane*8];     \
            bf16x8 bw = *(const bf16x8*)&s_w[OFF_BW1 + nt*512 + lane*8];     \
            f32x4 acc = mv;                                                  \
            acc = MFMA(ar, bs, acc);                                         \
            acc = MFMA(an, bw, acc);                                         \
            run[nt] = fmaxf(run[nt],                                         \
                      fmaxf(fmaxf(acc[0],acc[1]), fmaxf(acc[2],acc[3])));    \
        }                                                                    \
    }                                                                        \
    _Pragma("unroll")                                                        \
    for (int nt = 0; nt < 8; ++nt) {                                         \
        float m = fmaxf(run[nt], __shfl_xor(run[nt], 16));                   \
        float sel = (((g < 2) ? _kA : _kB) == 0) ? 0.f : (m + b1v[nt]);      \
        if (g == 0)      spool[(2*_q  )*136 + 16*nt + c16] = (__bf16)sel;    \
        else if (g == 2) spool[(2*_q+1)*136 + 16*nt + c16] = (__bf16)sel;    \
    }                                                                        \
} while (0)

    // pipeline prologue: pids for pairs 0-1, features for pair 0
    LOADP(0, 0);
    LOADF(0);
    LOADP(1, 1);

    STEP(0, 0, 1);
    STEP(1, 1, 0);
    STEP(2, 0, 1);
    STEP(3, 1, 0);
    STEP(4, 0, 1);
    STEP(5, 1, 0);
    STEP(6, 0, 1);
    STEP(7, 1, 0);

    // ---- conv for this wave's 16 voxels via MFMA (frags from LDS) ----
    asm volatile("s_waitcnt lgkmcnt(0)" ::: "memory");
    f32x4 o0 = {cb0, cb0, cb0, cb0};
    f32x4 o1 = {cb1, cb1, cb1, cb1};
    #pragma unroll
    for (int kk = 0; kk < 4; ++kk) {
        bf16x8 ap  = *(const bf16x8*)&spool[c16*136 + 32*kk + 8*g];
        bf16x8 bc0 = *(const bf16x8*)&s_w[OFF_CWF + kk*512       + lane*8];
        bf16x8 bc1 = *(const bf16x8*)&s_w[OFF_CWF + (4+kk)*512   + lane*8];
        o0 = MFMA(ap, bc0, o0);
        o1 = MFMA(ap, bc1, o1);
    }
    const int n  = tb16 >> 15;              // R3 = 2^15
    const int vb = tb16 & (R3 - 1);
    float* ob = out + (size_t)n*CC*R3 + (size_t)vb + 4*g;
    *(f32x4*)(ob + (size_t)c16*R3)        = o0;
    *(f32x4*)(ob + (size_t)(16 + c16)*R3) = o1;

#undef STEP
#undef LOADF
#undef LOADP
}

extern "C" void kernel_launch(void* const* d_in, const int* in_sizes, int n_in,
                              void* d_out, int out_size, void* d_ws, size_t ws_size,
                              hipStream_t stream)
{
    const float* points  = (const float*)d_in[0];
    const float* feature = (const float*)d_in[1];
    const float* fc0_w   = (const float*)d_in[2];
    const float* fc0_b   = (const float*)d_in[3];
    const float* fc1_w   = (const float*)d_in[4];
    const float* fc1_b   = (const float*)d_in[5];
    const float* sc_w    = (const float*)d_in[6];
    const float* conv_w  = (const float*)d_in[7];
    const float* conv_b  = (const float*)d_in[8];

    unsigned* count  = (unsigned*)d_ws;                       // 1 MB
    unsigned* bucket = count + NSEG;                          // 67 MB
    __bf16* wbuf = (__bf16*)(bucket + (size_t)NSEG * CAP);    // 26 KB
    float* out0 = (float*)d_out;                              // index (N,1,P) f32
    float* out1 = out0 + (size_t)NPTS;                        // feature_grid f32

    hipMemsetAsync(count, 0, (size_t)NSEG * sizeof(unsigned), stream);
    lpbe_bin <<<NPTS/256 + 1, 256, 0, stream>>>(points, count, bucket, out0,
                                                fc0_w, fc1_w, sc_w, conv_w, wbuf);
    lpbe_pool<<<NSEG/64, 256, 0, stream>>>(feature, fc0_b, fc1_b, conv_b,
                                           wbuf, count, bucket, out1);
}